// Round 6
// baseline (855.430 us; speedup 1.0000x reference)
//
#include <hip/hip_runtime.h>

// GRU scan: B=2048, T=2048, D=3, H=32. out[b,t] = h_new[b,t][0].
// Round-6: ZERO-LDS step. r1-r5 all plateau ~700-860us with VALUBusy~80% at
// 2 waves/SIMD -> model: per-step critical path ~440cyc dominated by the LDS
// h-exchange round trip (~240cyc). This round replaces it with in-register
// cross-lane ops:
//   - h valid in ALL 64 lanes (r AND z broadcast via permlane32_swap)
//   - per-step gather: 1x v_permlane16_swap(h,h) -> h[l&15] / h[16+(l&15)]
//     broadcast registers (~4cyc vs ~240)
//   - K-reduction as rotation systolic: 15x v_mov_dpp row_ror:1 interleaved
//     with 48 FMAs; weights pre-gathered in rotation order at init
//   - x: coalesced per-lane chunk load + compile-time v_readlane (no scalar
//     K$-miss stalls, no lgkm coupling), prefetch 1 chunk ahead
// DPP direction & permlane16 row convention are probed at runtime and folded
// into the init-time weight gather (self-calibrating, zero per-step cost).

#define GRU_B 2048
#define GRU_T 2048
#define GRU_D 3
#define GRU_H 32
#define CHUNK 16
#define NCHUNK (GRU_T / CHUNK)

typedef int v2i __attribute__((ext_vector_type(2)));

__device__ __forceinline__ float fast_sigmoid(float x) {
    float e = __expf(-x);                       // v_mul(log2e)+v_exp
    return __builtin_amdgcn_rcpf(1.0f + e);     // e=inf -> 0 (correct limit)
}
__device__ __forceinline__ float fast_tanh(float x) {
    float e = __expf(2.0f * x);                 // overflow -> inf -> tanh=1
    return 1.0f - 2.0f * __builtin_amdgcn_rcpf(e + 1.0f);
}

#if __has_builtin(__builtin_amdgcn_permlane32_swap)
#define HAVE_PL32 1
// lo_b = [v_lo32 broadcast], hi_b = [v_hi32 broadcast] (verified on HW in r5)
__device__ __forceinline__ void bcast32(float v, float& lo_b, float& hi_b) {
    v2i r = __builtin_amdgcn_permlane32_swap(__float_as_int(v), __float_as_int(v),
                                             false, false);
    lo_b = __int_as_float(r.x);
    hi_b = __int_as_float(r.y);
}
#else
#define HAVE_PL32 0
__device__ __forceinline__ float xor32f(float v) {
    int paddr = (int)((threadIdx.x ^ 32u) << 2);
    return __int_as_float(__builtin_amdgcn_ds_bpermute(paddr, __float_as_int(v)));
}
__device__ __forceinline__ void bcast32(float v, float& lo_b, float& hi_b) {
    float o = xor32f(v);
    bool lo = threadIdx.x < 32;
    lo_b = lo ? v : o;
    hi_b = lo ? o : v;
}
#endif

#if __has_builtin(__builtin_amdgcn_permlane16_swap)
#define HAVE_PL16 1
#endif

// rotate within 16-lane DPP rows by 1 (direction probed at runtime)
__device__ __forceinline__ float ror16(float v) {
    return __int_as_float(__builtin_amdgcn_update_dpp(
        __float_as_int(v), __float_as_int(v), 0x121 /*row_ror:1*/, 0xF, 0xF, false));
}
__device__ __forceinline__ float rdlanef(float v, int idx) {
    return __int_as_float(__builtin_amdgcn_readlane(__float_as_int(v), idx));
}

__global__ __launch_bounds__(64, 2) void gru_scan_kernel(
    const float* __restrict__ inp,     // [B, T, D]
    const float* __restrict__ w_ih,    // [3H, D]
    const float* __restrict__ w_hh,    // [3H, H]
    const float* __restrict__ bias,    // [3H]
    const float* __restrict__ bias_n,  // [H]
    float* __restrict__ out)           // [B, T]
{
    const int lane = threadIdx.x;        // 0..63
    const int unit = lane & 31;          // hidden unit owned
    const int half = lane >> 5;          // K-half id
    const int b    = blockIdx.x;
    const bool lo32 = (lane < 32);

    // ---- probe 1: DPP row_ror index step (delta = +1 or 15 (== -1 mod 16)) ----
    int delta;
    {
        int pv = lane & 15;
        int pr = __builtin_amdgcn_update_dpp(pv, pv, 0x121, 0xF, 0xF, false);
        delta = __builtin_amdgcn_readfirstlane(pr) & 15;  // value now at lane 0
    }
    // ---- probe 2: permlane16_swap row convention -> which K-window per half ----
    int kofs;  // my half's K-window base, consistent with per-step start register
#if HAVE_PL16
    {
        int qv = lane >> 4;  // 16-row index 0..3
        v2i r = __builtin_amdgcn_permlane16_swap(qv, qv, false, false);
        int convA = (__builtin_amdgcn_readfirstlane(r.x) == 0) ? 1 : 0;
        // convA: result.x holds even-row content -> half0 start = h[l&15] -> window 0
        kofs = (convA ? half : 1 - half) * 16;
    }
#else
    kofs = 16 * half;
#endif

    // Gate rows (sigma-split, proven r5): rowA = my sigmoid gate (r half0 /
    // z half1); rowB = other sigmoid gate (partial to exchange); rowC = n.
    const int rowA = unit + 32 * half;
    const int rowB = unit + 32 * (1 - half);
    const int rowC = 2 * GRU_H + unit;

    // ---- weights pre-gathered in ROTATION order: at systolic iter i the
    // rotating register holds h[kofs + ((lane + delta*i) & 15)] ----
    float wa[16], wb[16], wc[16];
#pragma unroll
    for (int i = 0; i < 16; ++i) {
        const int widx = kofs + ((lane + delta * i) & 15);
        wa[i] = w_hh[(size_t)rowA * GRU_H + widx];
        wb[i] = w_hh[(size_t)rowB * GRU_H + widx];
        wc[i] = w_hh[(size_t)rowC * GRU_H + widx];
    }
    float wia[GRU_D], wic[GRU_D];
#pragma unroll
    for (int d = 0; d < GRU_D; ++d) {
        wia[d] = w_ih[(size_t)rowA * GRU_D + d];
        wic[d] = w_ih[(size_t)rowC * GRU_D + d];
    }
    const float bA = bias[rowA];
    const float bC = bias[rowC] + bias_n[unit];

    const float* xb = inp + (size_t)b * GRU_T * GRU_D;
    float*       ob = out + (size_t)b * GRU_T;

    float h = 0.0f;       // valid full trajectory in ALL lanes (r & z broadcast)
    float outreg = 0.0f;  // lane s holds step (c*CHUNK+s)'s output

    // x chunk staging: lane i holds x_chunk[i] (48 floats), prefetch 1 ahead
    float vx = 0.0f;
    if (lane < CHUNK * GRU_D) vx = xb[lane];

    for (int c = 0; c < NCHUNK; ++c) {
        // prefetch next chunk (clamped; redundant load on last iter, harmless)
        const int cn = (c + 1 < NCHUNK) ? c + 1 : c;
        float vx_nxt = 0.0f;
        if (lane < CHUNK * GRU_D) vx_nxt = xb[cn * (CHUNK * GRU_D) + lane];

#pragma unroll
        for (int s = 0; s < CHUNK; ++s) {
            // ---- h window broadcast: 1 cross-lane op (no LDS) ----
            float rot;
#if HAVE_PL16
            {
                v2i r = __builtin_amdgcn_permlane16_swap(__float_as_int(h),
                                                         __float_as_int(h),
                                                         false, false);
                rot = lo32 ? __int_as_float(r.x) : __int_as_float(r.y);
            }
#else
            rot = __int_as_float(__builtin_amdgcn_ds_bpermute(
                (kofs + (lane & 15)) << 2, __float_as_int(h)));
#endif
            // x for this step (compile-time readlane, off the memory pipes)
            const float x0 = rdlanef(vx, 3 * s + 0);
            const float x1 = rdlanef(vx, 3 * s + 1);
            const float x2 = rdlanef(vx, 3 * s + 2);
            const float aM = fmaf(wia[2], x2, fmaf(wia[1], x1, fmaf(wia[0], x0, bA)));
            const float aN = fmaf(wic[2], x2, fmaf(wic[1], x1, fmaf(wic[0], x0, bC)));

            // ---- rotation-systolic K-half reduction: 48 FMA + 15 DPP movs ----
            float A = 0.0f, Bp = 0.0f, Cp = 0.0f;
#pragma unroll
            for (int k = 0; k < 16; ++k) {
                A  = fmaf(wa[k], rot, A);
                Bp = fmaf(wb[k], rot, Bp);
                Cp = fmaf(wc[k], rot, Cp);
                if (k < 15) rot = ror16(rot);
            }

            // ---- combine halves (register cross-lane, proven r5) ----
            float cLo, cHi; bcast32(Cp, cLo, cHi);
            const float gN = cLo + cHi;                    // full n dot, all lanes
            float bLo, bHi; bcast32(Bp, bLo, bHi);
            const float gM = aM + A + (lo32 ? bHi : bLo);  // my sigmoid gate, full

            const float sg = fast_sigmoid(gM);             // half0: r, half1: z
            float rAll, zAll; bcast32(sg, rAll, zAll);     // r and z in all lanes

            const float n = fast_tanh(fmaf(rAll, gN, aN)); // valid in ALL lanes
            h = fmaf(zAll, h - n, n);                      // valid in ALL lanes

            // ---- output capture: h[0] lives in lane 0 ----
            const float h0 = rdlanef(h, 0);
            if (lane == s) outreg = h0;
        }

        if (lane < CHUNK) ob[c * CHUNK + lane] = outreg;   // coalesced store
        vx = vx_nxt;
    }
}

extern "C" void kernel_launch(void* const* d_in, const int* in_sizes, int n_in,
                              void* d_out, int out_size, void* d_ws, size_t ws_size,
                              hipStream_t stream) {
    const float* inp    = (const float*)d_in[0];
    const float* w_ih   = (const float*)d_in[1];
    const float* w_hh   = (const float*)d_in[2];
    const float* bias   = (const float*)d_in[3];
    const float* bias_n = (const float*)d_in[4];
    float* out = (float*)d_out;

    dim3 grid(GRU_B);
    dim3 block(64);
    gru_scan_kernel<<<grid, block, 0, stream>>>(inp, w_ih, w_hh, bias, bias_n, out);
}